// Round 4
// baseline (1057.566 us; speedup 1.0000x reference)
//
#include <hip/hip_runtime.h>
#include <stdint.h>

// ---------------- problem constants ----------------
#define NP   250000
#define NA   10000
#define NBLK 5
#define NL   20            // 5 blocks x (2 iW + 2 oW) layers
#define BLOB_W_BYTES 32768               // 128x128 bf16, row=out-feature, XOR-swizzled chunks
#define BLOB_BYTES   33280               // + 128 fp32 pre-scaled biases (512 B)

#define LOG2E 1.4426950408889634f
#define LN2   0.6931471805599453f

typedef __bf16 bf16x8 __attribute__((ext_vector_type(8)));
typedef float  f32x4  __attribute__((ext_vector_type(4)));
typedef unsigned short ushort_t;
typedef unsigned int   uint_t;
typedef int4  i4_ma __attribute__((may_alias));
typedef uint2 u2_ma __attribute__((may_alias));

// ---------------- static device scratch ----------------
__device__ uint8_t g_blob[NL * BLOB_BYTES];     // transposed+swizzled bf16 weights + f32 biases
__device__ float   g_outs[NBLK * NA * 2];       // per-block per-atom segment sums
__device__ float   g_nh[1];
__device__ float   g_Rf[NA * 3];
__device__ float   g_oWfF[NBLK * 128 * 2];
__device__ float   g_oBfF[NBLK * 2];
__device__ float   g_scF[190];
__device__ float   g_shF[190];

static __device__ __forceinline__ float bf2f(ushort_t u) {
    return __uint_as_float(((uint_t)u) << 16);
}
static __device__ __forceinline__ ushort_t f2bf(float f) {
    uint_t u = __float_as_uint(f);
    u += 0x7fffu + ((u >> 16) & 1u);   // RNE
    return (ushort_t)(u >> 16);
}
static __device__ __forceinline__ bf16x8 as_bf16x8(i4_ma v) {
    union { i4_ma i; bf16x8 b; } u; u.i = v; return u.b;
}
// ssp(x + b) - ln2 with bias pre-scaled by log2e:  (log2(1+2^t) - 1) * ln2
static __device__ __forceinline__ float ssp_core(float acc, float bias_scaled) {
    float t = fmaf(acc, LOG2E, bias_scaled);
    return fmaf(log2f(1.0f + exp2f(t)), LN2, -LN2);
}

// dtype detection: probe even 16-bit halves of first 512 halves of iW as bf16.
// Genuine bf16 weights (~N(0,0.05)): all |v| <= ~0.3. If iW is f32, even halves
// are mantissa bits -> ~uniform exponents -> some |v| > 64 w.p. 1-1e-70.
static __device__ __forceinline__ bool detect_is_f32(const ushort_t* probe) {
    __shared__ int flag;
    if (threadIdx.x == 0) flag = 0;
    __syncthreads();
    if (threadIdx.x < 256) {
        float v = fabsf(bf2f(probe[2 * threadIdx.x]));
        if (!(v <= 64.0f)) flag = 1;   // catches NaN too
    }
    __syncthreads();
    return flag != 0;
}
static __device__ __forceinline__ float in_elt(const void* p, int i, bool isf32) {
    return isf32 ? ((const float*)p)[i] : bf2f(((const ushort_t*)p)[i]);
}

// ---------------- zero accumulators ----------------
__global__ void zero_outs()
{
    const int t = blockIdx.x * 256 + threadIdx.x;
    if (t < NBLK * NA * 2) g_outs[t] = 0.0f;
    if (t == 0) g_nh[0] = 0.0f;
}

// ---------------- weight prep: transpose + XOR-swizzle + bias scale ----------------
// blob[L]: row m (out-feature) * 128 bf16; chunk c=k>>3 stored at 8*((k>>3)^(m&15))+(k&7)
__global__ void prep_weights(const void* __restrict__ iW, const void* __restrict__ iB,
                             const void* __restrict__ oW, const void* __restrict__ oB)
{
    const bool isf32 = detect_is_f32((const ushort_t*)iW);
    const int L = blockIdx.x;           // 0..19
    const int b = L >> 2, li = L & 3;
    const void* srcW = (li < 2) ? iW : oW;
    const void* srcB = (li < 2) ? iB : oB;
    const int lyr = (li < 2) ? (b * 2 + li) : (b * 2 + li - 2);
    const int wofs = lyr * 16384;
    const int bofs = lyr * 128;
    uint8_t* blob = g_blob + (size_t)L * BLOB_BYTES;
    ushort_t* dw = (ushort_t*)blob;
    float*    db = (float*)(blob + BLOB_W_BYTES);
    for (int idx = threadIdx.x; idx < 16384; idx += blockDim.x) {
        int k = idx >> 7, n = idx & 127;               // src: W[k][n] (k=in, n=out)
        dw[n * 128 + 8 * ((k >> 3) ^ (n & 15)) + (k & 7)] =
            f2bf(in_elt(srcW, wofs + k * 128 + n, isf32));
    }
    for (int m = threadIdx.x; m < 128; m += blockDim.x)
        db[m] = in_elt(srcB, bofs + m, isf32) * LOG2E;
}

// canonical f32 copies of the small tensors (exact whichever the input dtype is)
__global__ void prep_misc(const void* __restrict__ R, const void* __restrict__ oWf,
                          const void* __restrict__ oBf, const void* __restrict__ scales,
                          const void* __restrict__ shifts, const void* __restrict__ iW)
{
    const bool isf32 = detect_is_f32((const ushort_t*)iW);
    const int t = blockIdx.x * 256 + threadIdx.x;
    if (t < NA * 3)      g_Rf[t]   = in_elt(R, t, isf32);
    if (t < NBLK * 256)  g_oWfF[t] = in_elt(oWf, t, isf32);
    if (t < NBLK * 2)    g_oBfF[t] = in_elt(oBf, t, isf32);
    if (t < 190)         g_scF[t]  = in_elt(scales, t, isf32);
    if (t < 190)         g_shF[t]  = in_elt(shifts, t, isf32);
}

// ---------------- fused per-pair MLP ----------------
// one wave = 64 pairs; ping-pong LDS act buffers, wave-private => no barriers.
__global__ __launch_bounds__(64, 2)
void pairs_mlp_kernel(const int* __restrict__ idx_i,
                      const int* __restrict__ idx_j,
                      float* __restrict__ out_rij)       // d_out + 20000 (f32)
{
    __shared__ i4_ma actx[64 * 16];     // 64 rows x 128 bf16 (16 x int4 chunks), swizzled
    __shared__ i4_ma acty[64 * 16];

    const int lane = threadIdx.x;
    const int p0 = blockIdx.x * 64;
    const int p = p0 + lane;
    const bool valid = (p < NP);

    // ---- phase 0: rij + radial basis -> actx (swizzled rows) ----
    int ai = 0, aj = 0;
    if (valid) { ai = idx_i[p]; aj = idx_j[p]; }
    float xi0 = g_Rf[3 * ai + 0], xi1 = g_Rf[3 * ai + 1], xi2 = g_Rf[3 * ai + 2];
    float xj0 = g_Rf[3 * aj + 0], xj1 = g_Rf[3 * aj + 1], xj2 = g_Rf[3 * aj + 2];
    float dx = xj0 - xi0, dy = xj1 - xi1, dz = xj2 - xi2;
    float rij = sqrtf(dx * dx + dy * dy + dz * dz + 1e-12f);
    if (valid) out_rij[p] = rij;

    float fcut = 0.0f;
    if (valid && rij < 10.0f) {
        float xc = rij * 0.1f;
        float x3 = xc * xc * xc;
        fcut = 1.0f + x3 * (-10.0f + xc * (15.0f - 6.0f * xc));
    }
    const float mu0 = 4.5399929762484854e-05f;
    const float dmu = (1.0f - mu0) / 127.0f;
    const float wc = (2.0f / 128.0f) * (1.0f - mu0);
    const float NW2 = -(1.0f / (wc * wc)) * LOG2E;      // -width*log2e
    float er = exp2f(-rij * LOG2E);                      // exp(-rij)
    const int rsw = lane & 15;
    for (int c = 0; c < 16; ++c) {
        ushort_t v[8];
#pragma unroll
        for (int j = 0; j < 8; ++j) {
            float mu = mu0 + (float)(c * 8 + j) * dmu;
            float d = er - mu;
            v[j] = f2bf(fcut * exp2f(NW2 * d * d));
        }
        i4_ma pk;
        pk.x = (int)v[0] | ((int)v[1] << 16);
        pk.y = (int)v[2] | ((int)v[3] << 16);
        pk.z = (int)v[4] | ((int)v[5] << 16);
        pk.w = (int)v[6] | ((int)v[7] << 16);
        actx[lane * 16 + (c ^ rsw)] = pk;
    }

    const int q = lane >> 4;        // quad
    const int l15 = lane & 15;

    for (int blk = 0; blk < NBLK; ++blk) {
#pragma unroll
        for (int li = 0; li < 4; ++li) {
            const int L = blk * 4 + li;
            const uint8_t* blob = g_blob + (size_t)L * BLOB_BYTES;
            const ushort_t* bw = (const ushort_t*)blob;
            const float* bb = (const float*)(blob + BLOB_W_BYTES);
            // strict ping-pong: li0 x->y, li1 y->x (x2 stays in actx for next block),
            // li2 x->y, li3 reads y (head).
            const i4_ma* src = (li & 1) ? acty : actx;
            i4_ma* dst = (li & 1) ? actx : acty;

            f32x4 acc[4][8];
#pragma unroll
            for (int nt = 0; nt < 4; ++nt)
#pragma unroll
                for (int mt = 0; mt < 8; ++mt) {
                    f32x4 z = {0.f, 0.f, 0.f, 0.f};
                    acc[nt][mt] = z;
                }
#pragma unroll
            for (int kt = 0; kt < 4; ++kt) {
                bf16x8 afr[8], bfr[4];
                const int cc = kt * 4 + q;
#pragma unroll
                for (int mt = 0; mt < 8; ++mt) {
                    int m = mt * 16 + l15;
                    afr[mt] = as_bf16x8(*(const i4_ma*)(bw + m * 128 + 8 * (cc ^ (m & 15))));
                }
#pragma unroll
                for (int nt = 0; nt < 4; ++nt) {
                    int r = nt * 16 + l15;
                    bfr[nt] = as_bf16x8(src[r * 16 + (cc ^ (r & 15))]);
                }
#pragma unroll
                for (int nt = 0; nt < 4; ++nt)
#pragma unroll
                    for (int mt = 0; mt < 8; ++mt)
                        acc[nt][mt] = __builtin_amdgcn_mfma_f32_16x16x32_bf16(
                            afr[mt], bfr[nt], acc[nt][mt], 0, 0, 0);
            }

            f32x4 bias[8];
#pragma unroll
            for (int mt = 0; mt < 8; ++mt)
                bias[mt] = *(const f32x4*)(bb + mt * 16 + q * 4);

            if (li < 3) {
                // acc[nt][mt][rr] = feature (mt*16+q*4+rr) of pair (nt*16+l15)
#pragma unroll
                for (int nt = 0; nt < 4; ++nt) {
                    const int rp = nt * 16 + l15;
                    const int rs = rp & 15;
#pragma unroll
                    for (int mt = 0; mt < 8; ++mt) {
                        ushort_t h[4];
#pragma unroll
                        for (int rr = 0; rr < 4; ++rr)
                            h[rr] = f2bf(ssp_core(acc[nt][mt][rr], bias[mt][rr]));
                        u2_ma pk;
                        pk.x = (uint_t)h[0] | ((uint_t)h[1] << 16);
                        pk.y = (uint_t)h[2] | ((uint_t)h[3] << 16);
                        const int c = mt * 2 + (q >> 1);   // feature chunk
                        ((u2_ma*)&dst[rp * 16 + (c ^ rs)])[q & 1] = pk;
                    }
                }
            } else {
                // head: out_e = y @ oWf[blk] + oBf[blk], fused + segment-sum atomics
                const float* hw = g_oWfF + blk * 256;
                const float ob0 = g_oBfF[blk * 2 + 0];
                const float ob1 = g_oBfF[blk * 2 + 1];
#pragma unroll
                for (int nt = 0; nt < 4; ++nt) {
                    float h0 = 0.f, h1 = 0.f;
#pragma unroll
                    for (int mt = 0; mt < 8; ++mt) {
#pragma unroll
                        for (int rr = 0; rr < 4; ++rr) {
                            float y = ssp_core(acc[nt][mt][rr], bias[mt][rr]);
                            const int f = mt * 16 + q * 4 + rr;
                            h0 = fmaf(y, hw[f * 2 + 0], h0);
                            h1 = fmaf(y, hw[f * 2 + 1], h1);
                        }
                    }
                    h0 += __shfl_xor(h0, 16, 64);
                    h0 += __shfl_xor(h0, 32, 64);
                    h1 += __shfl_xor(h1, 16, 64);
                    h1 += __shfl_xor(h1, 32, 64);
                    int aseg = __shfl(ai, nt * 16 + l15, 64);
                    int psel = p0 + nt * 16 + l15;
                    if (q == 0 && psel < NP) {
                        atomicAdd(&g_outs[(blk * NA + aseg) * 2 + 0], h0 + ob0);
                        atomicAdd(&g_outs[(blk * NA + aseg) * 2 + 1], h1 + ob1);
                    }
                }
            }
        }
    }
}

// ---------------- finalize: scale/shift + nhloss reduction ----------------
__global__ void finalize_kernel(const int* __restrict__ Z,
                                float* __restrict__ out_atoms)   // d_out (f32)
{
    __shared__ float red[256];
    const int a = blockIdx.x * 256 + threadIdx.x;
    float s = 0.f;
    if (a < NA) {
        float v[NBLK][2];
        float t0 = 0.f, t1 = 0.f;
#pragma unroll
        for (int b = 0; b < NBLK; ++b) {
            v[b][0] = g_outs[(b * NA + a) * 2 + 0];
            v[b][1] = g_outs[(b * NA + a) * 2 + 1];
            t0 += v[b][0]; t1 += v[b][1];
        }
        const int z = Z[a];
        out_atoms[a * 2 + 0] = t0 * g_scF[z]      + g_shF[z];
        out_atoms[a * 2 + 1] = t1 * g_scF[95 + z] + g_shF[95 + z];
#pragma unroll
        for (int b = 1; b < NBLK; ++b)
#pragma unroll
            for (int o = 0; o < 2; ++o) {
                float x2 = v[b][o] * v[b][o];
                float p2 = v[b - 1][o] * v[b - 1][o];
                s += x2 / (x2 + p2 + 1e-7f);
            }
    }
    red[threadIdx.x] = s;
    __syncthreads();
    for (int st = 128; st > 0; st >>= 1) {
        if (threadIdx.x < st) red[threadIdx.x] += red[threadIdx.x + st];
        __syncthreads();
    }
    if (threadIdx.x == 0) atomicAdd(&g_nh[0], red[0]);
}

__global__ void nh_write(float* __restrict__ out_nh)
{
    out_nh[0] = g_nh[0] * (1.0f / 20000.0f);
}

// ---------------- launch ----------------
extern "C" void kernel_launch(void* const* d_in, const int* in_sizes, int n_in,
                              void* d_out, int out_size, void* d_ws, size_t ws_size,
                              hipStream_t stream)
{
    const int* Z     = (const int*)d_in[0];
    const void* R    = d_in[1];
    const int* idx_i = (const int*)d_in[2];
    const int* idx_j = (const int*)d_in[3];
    const void* iW   = d_in[4];
    const void* iB   = d_in[5];
    const void* oW   = d_in[6];
    const void* oB   = d_in[7];
    const void* oWf  = d_in[8];
    const void* oBf  = d_in[9];
    const void* scales = d_in[10];
    const void* shifts = d_in[11];

    float* out_f = (float*)d_out;   // [0,20000): outputs  [20000,270000): rij  [270000]: nhloss

    zero_outs<<<(NBLK * NA * 2 + 255) / 256, 256, 0, stream>>>();
    prep_weights<<<NL, 256, 0, stream>>>(iW, iB, oW, oB);
    prep_misc<<<(NA * 3 + 255) / 256, 256, 0, stream>>>(R, oWf, oBf, scales, shifts, iW);
    pairs_mlp_kernel<<<(NP + 63) / 64, 64, 0, stream>>>(idx_i, idx_j, out_f + 2 * NA);
    finalize_kernel<<<(NA + 255) / 256, 256, 0, stream>>>(Z, out_f);
    nh_write<<<1, 1, 0, stream>>>(out_f + 2 * NA + NP);
}

// Round 6
// 639.474 us; speedup vs baseline: 1.6538x; 1.6538x over previous
//
#include <hip/hip_runtime.h>
#include <stdint.h>

// ---------------- problem constants ----------------
#define NP   250000
#define NA   10000
#define NBLK 5
#define NL   20            // 5 blocks x (2 iW + 2 oW) layers
#define BLOB_W_BYTES 32768               // 128x128 bf16, row=out-feature, XOR-swizzled chunks
#define BLOB_BYTES   33280               // + 128 fp32 folded biases (512 B)

#define LOG2E 1.4426950408889634f
#define LN2   0.6931471805599453f

typedef __bf16 bf16x8 __attribute__((ext_vector_type(8)));
typedef float  f32x4  __attribute__((ext_vector_type(4)));
typedef unsigned short ushort_t;
typedef unsigned int   uint_t;
typedef int4  i4_ma __attribute__((may_alias));
typedef uint2 u2_ma __attribute__((may_alias));

// ---------------- static device scratch ----------------
__device__ uint8_t g_blob[NL * BLOB_BYTES];   // swizzled bf16 weights + folded f32 biases
__device__ float   g_outs[NBLK * NA * 2];     // per-block per-atom segment sums
__device__ float   g_nh[1];
__device__ float   g_Rf[NA * 3];
__device__ float   g_oWfF[NBLK * 128 * 2];    // ln2-prescaled head weights
__device__ float   g_oBfF[NBLK * 2];          // head biases (unmodified)
__device__ float   g_scF[190];
__device__ float   g_shF[190];

static __device__ __forceinline__ float bf2f(ushort_t u) {
    return __uint_as_float(((uint_t)u) << 16);
}
static __device__ __forceinline__ ushort_t f2bf(float f) {   // RNE (prep only)
    uint_t u = __float_as_uint(f);
    u += 0x7fffu + ((u >> 16) & 1u);
    return (ushort_t)(u >> 16);
}
static __device__ __forceinline__ bf16x8 as_bf16x8(i4_ma v) {
    union { i4_ma i; bf16x8 b; } u; u.i = v; return u.b;
}
// pack 2 floats -> bf16x2 dword by truncation (1 VALU op). Truncation has
// RELATIVE error (2^-9 bias) -- safe because stored u decays with the signal.
static __device__ __forceinline__ uint_t pkbf(float a, float b) {
    return __byte_perm(__float_as_uint(a), __float_as_uint(b), 0x7632);
}
// stored activation: u = log2(1+2^t) - 1 = y/ln2 (near-zero like y).
// Folding: t_next = u@W + b*log2e (W unscaled); head: out = u@(ln2*oWf) + oBf.
static __device__ __forceinline__ float ssp_u(float t) {
    return log2f(1.0f + exp2f(t)) - 1.0f;
}

// dtype auto-detection (validated round 4: inputs are f32; keep as insurance)
static __device__ __forceinline__ bool detect_is_f32(const ushort_t* probe) {
    __shared__ int flag;
    if (threadIdx.x == 0) flag = 0;
    __syncthreads();
    if (threadIdx.x < 256) {
        float v = fabsf(bf2f(probe[2 * threadIdx.x]));
        if (!(v <= 64.0f)) flag = 1;
    }
    __syncthreads();
    return flag != 0;
}
static __device__ __forceinline__ float in_elt(const void* p, int i, bool isf32) {
    return isf32 ? ((const float*)p)[i] : bf2f(((const ushort_t*)p)[i]);
}

// ---------------- zero accumulators ----------------
__global__ void zero_outs()
{
    const int t = blockIdx.x * 256 + threadIdx.x;
    if (t < NBLK * NA * 2) g_outs[t] = 0.0f;
    if (t == 0) g_nh[0] = 0.0f;
}

// ---------------- weight prep ----------------
// blob[L]: row m (out-feature) * 128 bf16; chunk c=k>>3 at 8*((k>>3)^(m&15))+(k&7).
// L==0: W prescaled by log2e (input is raw basis). L>=1: W unscaled (input is u).
// bias always b*log2e.
__global__ void prep_weights(const void* __restrict__ iW, const void* __restrict__ iB,
                             const void* __restrict__ oW, const void* __restrict__ oB)
{
    const bool isf32 = detect_is_f32((const ushort_t*)iW);
    const int L = blockIdx.x;           // 0..19
    const int b = L >> 2, li = L & 3;
    const void* srcW = (li < 2) ? iW : oW;
    const void* srcB = (li < 2) ? iB : oB;
    const int lyr = (li < 2) ? (b * 2 + li) : (b * 2 + li - 2);
    const int wofs = lyr * 16384;
    const int bofs = lyr * 128;
    uint8_t* blob = g_blob + (size_t)L * BLOB_BYTES;
    ushort_t* dw = (ushort_t*)blob;
    float*    db = (float*)(blob + BLOB_W_BYTES);
    for (int idx = threadIdx.x; idx < 16384; idx += blockDim.x) {
        int k = idx >> 7, n = idx & 127;               // src: W[k][n] (k=in, n=out)
        float w = in_elt(srcW, wofs + k * 128 + n, isf32);
        if (L == 0) w *= LOG2E;
        dw[n * 128 + 8 * ((k >> 3) ^ (n & 15)) + (k & 7)] = f2bf(w);
    }
    for (int m = threadIdx.x; m < 128; m += blockDim.x)
        db[m] = in_elt(srcB, bofs + m, isf32) * LOG2E;
}

// canonical f32 copies; head weights prescaled by ln2 (u -> y factor)
__global__ void prep_misc(const void* __restrict__ R, const void* __restrict__ oWf,
                          const void* __restrict__ oBf, const void* __restrict__ scales,
                          const void* __restrict__ shifts, const void* __restrict__ iW)
{
    const bool isf32 = detect_is_f32((const ushort_t*)iW);
    const int t = blockIdx.x * 256 + threadIdx.x;
    if (t < NA * 3)      g_Rf[t]   = in_elt(R, t, isf32);
    if (t < NBLK * 256)  g_oWfF[t] = LN2 * in_elt(oWf, t, isf32);
    if (t < NBLK * 2)    g_oBfF[t] = in_elt(oBf, t, isf32);
    if (t < 190)         g_scF[t]  = in_elt(scales, t, isf32);
    if (t < 190)         g_shF[t]  = in_elt(shifts, t, isf32);
}

// ---------------- fused per-pair MLP ----------------
// one wave = 32 pairs; 2 x 8KB ping-pong LDS (wave-private, no barriers).
// 16KB LDS/wg -> 10 wg/CU (LDS is the binding occupancy cap).
__global__ __launch_bounds__(64, 3)
void pairs_mlp_kernel(const int* __restrict__ idx_i,
                      const int* __restrict__ idx_j,
                      float* __restrict__ out_rij)       // d_out + 20000 (f32)
{
    __shared__ i4_ma actx[32 * 16];     // 32 rows x 128 bf16, XOR-swizzled 16B chunks
    __shared__ i4_ma acty[32 * 16];

    const int lane = threadIdx.x;
    const int pp = lane & 31;           // pair owned (both half-waves mirror)
    const int p0 = blockIdx.x * 32;
    const int p = p0 + pp;
    const bool valid = (p < NP);

    // ---- phase 0: rij + radial basis -> actx ----
    int ai = 0, aj = 0;
    if (valid) { ai = idx_i[p]; aj = idx_j[p]; }
    float xi0 = g_Rf[3 * ai + 0], xi1 = g_Rf[3 * ai + 1], xi2 = g_Rf[3 * ai + 2];
    float xj0 = g_Rf[3 * aj + 0], xj1 = g_Rf[3 * aj + 1], xj2 = g_Rf[3 * aj + 2];
    float dx = xj0 - xi0, dy = xj1 - xi1, dz = xj2 - xi2;
    float rij = sqrtf(dx * dx + dy * dy + dz * dz + 1e-12f);
    if (lane < 32 && valid) out_rij[p] = rij;

    float fcut = 0.0f;
    if (valid && rij < 10.0f) {
        float xc = rij * 0.1f;
        float x3 = xc * xc * xc;
        fcut = 1.0f + x3 * (-10.0f + xc * (15.0f - 6.0f * xc));
    }
    const float mu0 = 4.5399929762484854e-05f;
    const float dmu = (1.0f - mu0) / 127.0f;
    const float wc = (2.0f / 128.0f) * (1.0f - mu0);
    const float NW2 = -(1.0f / (wc * wc)) * LOG2E;
    float er = exp2f(-rij * LOG2E);
    const int rs = pp & 15;
    const int c0 = (lane >> 5) * 8;     // each half-wave writes 8 of 16 chunks
#pragma unroll
    for (int ci = 0; ci < 8; ++ci) {
        const int c = c0 + ci;
        uint_t d[4];
#pragma unroll
        for (int jj = 0; jj < 4; ++jj) {
            float m0 = mu0 + (float)(c * 8 + jj * 2 + 0) * dmu;
            float m1 = mu0 + (float)(c * 8 + jj * 2 + 1) * dmu;
            float e0 = er - m0, e1 = er - m1;
            d[jj] = pkbf(fcut * exp2f(NW2 * e0 * e0), fcut * exp2f(NW2 * e1 * e1));
        }
        i4_ma pk;
        pk.x = (int)d[0]; pk.y = (int)d[1]; pk.z = (int)d[2]; pk.w = (int)d[3];
        actx[pp * 16 + (c ^ rs)] = pk;
    }

    const int q = lane >> 4;        // quad
    const int l15 = lane & 15;
    const int aseg = valid ? ai : -1;   // sentinel so invalid pairs never merge/fire

    for (int blk = 0; blk < NBLK; ++blk) {
#pragma unroll
        for (int li = 0; li < 4; ++li) {
            const int L = blk * 4 + li;
            const uint8_t* blob = g_blob + (size_t)L * BLOB_BYTES;
            const ushort_t* bw = (const ushort_t*)blob;
            const float* bb = (const float*)(blob + BLOB_W_BYTES);
            // li0: actx->acty, li1: acty->actx (x carries), li2: actx->acty, li3: reads acty
            const i4_ma* src = (li & 1) ? acty : actx;
            i4_ma* dst = (li & 1) ? actx : acty;

            f32x4 acc[2][8];
#pragma unroll
            for (int nt = 0; nt < 2; ++nt)
#pragma unroll
                for (int mt = 0; mt < 8; ++mt) {
                    f32x4 z = {0.f, 0.f, 0.f, 0.f};
                    acc[nt][mt] = z;
                }
#pragma unroll
            for (int kt = 0; kt < 4; ++kt) {
                const int cc = kt * 4 + q;
                bf16x8 bfr0 = as_bf16x8(src[(l15) * 16 + (cc ^ l15)]);
                bf16x8 bfr1 = as_bf16x8(src[(16 + l15) * 16 + (cc ^ l15)]);
#pragma unroll
                for (int mt = 0; mt < 8; ++mt) {
                    bf16x8 afr = as_bf16x8(
                        *(const i4_ma*)(bw + (mt * 16 + l15) * 128 + 8 * (cc ^ l15)));
                    acc[0][mt] = __builtin_amdgcn_mfma_f32_16x16x32_bf16(
                        afr, bfr0, acc[0][mt], 0, 0, 0);
                    acc[1][mt] = __builtin_amdgcn_mfma_f32_16x16x32_bf16(
                        afr, bfr1, acc[1][mt], 0, 0, 0);
                }
            }

            if (li < 3) {
                // acc[nt][mt][rr] = feature (mt*16+q*4+rr) of pair (nt*16+l15)
#pragma unroll
                for (int mt = 0; mt < 8; ++mt) {
                    const f32x4 bias = *(const f32x4*)(bb + mt * 16 + q * 4);
                    const int c = mt * 2 + (q >> 1);   // feature chunk
#pragma unroll
                    for (int nt = 0; nt < 2; ++nt) {
                        float u0 = ssp_u(acc[nt][mt][0] + bias[0]);
                        float u1 = ssp_u(acc[nt][mt][1] + bias[1]);
                        float u2 = ssp_u(acc[nt][mt][2] + bias[2]);
                        float u3 = ssp_u(acc[nt][mt][3] + bias[3]);
                        u2_ma pk;
                        pk.x = pkbf(u0, u1);
                        pk.y = pkbf(u2, u3);
                        const int rp = nt * 16 + l15;
                        ((u2_ma*)&dst[rp * 16 + (c ^ l15)])[q & 1] = pk;
                    }
                }
            } else {
                // head: out_e = u3 @ (ln2*oWf) + oBf, then sorted-segment reduction
                const float* hw = g_oWfF + blk * 256;
                const float ob0 = g_oBfF[blk * 2 + 0];
                const float ob1 = g_oBfF[blk * 2 + 1];
                float hs[2][2];
#pragma unroll
                for (int nt = 0; nt < 2; ++nt) {
                    float h0 = 0.f, h1 = 0.f;
#pragma unroll
                    for (int mt = 0; mt < 8; ++mt) {
                        const f32x4 bias = *(const f32x4*)(bb + mt * 16 + q * 4);
#pragma unroll
                        for (int rr = 0; rr < 4; ++rr) {
                            float u = ssp_u(acc[nt][mt][rr] + bias[rr]);
                            const int f = mt * 16 + q * 4 + rr;
                            h0 = fmaf(u, hw[f * 2 + 0], h0);
                            h1 = fmaf(u, hw[f * 2 + 1], h1);
                        }
                    }
                    // butterfly over quads: every lane ends with pair (nt*16+l15)'s total
                    h0 += __shfl_xor(h0, 16, 64);
                    h0 += __shfl_xor(h0, 32, 64);
                    h1 += __shfl_xor(h1, 16, 64);
                    h1 += __shfl_xor(h1, 32, 64);
                    hs[nt][0] = h0; hs[nt][1] = h1;
                }
                // lane pp now selects ITS pair's totals
                float c0v = (pp < 16) ? hs[0][0] : hs[1][0];
                float c1v = (pp < 16) ? hs[0][1] : hs[1][1];
                c0v += ob0; c1v += ob1;
                // segmented inclusive scan over the 32 sorted pairs (runs contiguous)
#pragma unroll
                for (int d = 1; d < 32; d <<= 1) {
                    float t0 = __shfl_up(c0v, d, 64);
                    float t1 = __shfl_up(c1v, d, 64);
                    int   an = __shfl_up(aseg, d, 64);
                    if (pp >= d && an == aseg) { c0v += t0; c1v += t1; }
                }
                int ain = __shfl_down(aseg, 1, 64);
                bool tail = (pp == 31) || (ain != aseg);
                if (lane < 32 && valid && tail) {
                    atomicAdd(&g_outs[(blk * NA + aseg) * 2 + 0], c0v);
                    atomicAdd(&g_outs[(blk * NA + aseg) * 2 + 1], c1v);
                }
            }
        }
    }
}

// ---------------- finalize: scale/shift + nhloss reduction ----------------
__global__ void finalize_kernel(const int* __restrict__ Z,
                                float* __restrict__ out_atoms)   // d_out (f32)
{
    __shared__ float red[256];
    const int a = blockIdx.x * 256 + threadIdx.x;
    float s = 0.f;
    if (a < NA) {
        float v[NBLK][2];
        float t0 = 0.f, t1 = 0.f;
#pragma unroll
        for (int b = 0; b < NBLK; ++b) {
            v[b][0] = g_outs[(b * NA + a) * 2 + 0];
            v[b][1] = g_outs[(b * NA + a) * 2 + 1];
            t0 += v[b][0]; t1 += v[b][1];
        }
        const int z = Z[a];
        out_atoms[a * 2 + 0] = t0 * g_scF[z]      + g_shF[z];
        out_atoms[a * 2 + 1] = t1 * g_scF[95 + z] + g_shF[95 + z];
#pragma unroll
        for (int b = 1; b < NBLK; ++b)
#pragma unroll
            for (int o = 0; o < 2; ++o) {
                float x2 = v[b][o] * v[b][o];
                float p2 = v[b - 1][o] * v[b - 1][o];
                s += x2 / (x2 + p2 + 1e-7f);
            }
    }
    red[threadIdx.x] = s;
    __syncthreads();
    for (int st = 128; st > 0; st >>= 1) {
        if (threadIdx.x < st) red[threadIdx.x] += red[threadIdx.x + st];
        __syncthreads();
    }
    if (threadIdx.x == 0) atomicAdd(&g_nh[0], red[0]);
}

__global__ void nh_write(float* __restrict__ out_nh)
{
    out_nh[0] = g_nh[0] * (1.0f / 20000.0f);
}

// ---------------- launch ----------------
extern "C" void kernel_launch(void* const* d_in, const int* in_sizes, int n_in,
                              void* d_out, int out_size, void* d_ws, size_t ws_size,
                              hipStream_t stream)
{
    const int* Z     = (const int*)d_in[0];
    const void* R    = d_in[1];
    const int* idx_i = (const int*)d_in[2];
    const int* idx_j = (const int*)d_in[3];
    const void* iW   = d_in[4];
    const void* iB   = d_in[5];
    const void* oW   = d_in[6];
    const void* oB   = d_in[7];
    const void* oWf  = d_in[8];
    const void* oBf  = d_in[9];
    const void* scales = d_in[10];
    const void* shifts = d_in[11];

    float* out_f = (float*)d_out;   // [0,20000): outputs  [20000,270000): rij  [270000]: nhloss

    zero_outs<<<(NBLK * NA * 2 + 255) / 256, 256, 0, stream>>>();
    prep_weights<<<NL, 256, 0, stream>>>(iW, iB, oW, oB);
    prep_misc<<<(NA * 3 + 255) / 256, 256, 0, stream>>>(R, oWf, oBf, scales, shifts, iW);
    pairs_mlp_kernel<<<(NP + 31) / 32, 64, 0, stream>>>(idx_i, idx_j, out_f + 2 * NA);
    finalize_kernel<<<(NA + 255) / 256, 256, 0, stream>>>(Z, out_f);
    nh_write<<<1, 1, 0, stream>>>(out_f + 2 * NA + NP);
}

// Round 7
// 534.436 us; speedup vs baseline: 1.9788x; 1.1965x over previous
//
#include <hip/hip_runtime.h>
#include <stdint.h>

// ---------------- problem constants ----------------
#define NP   250000
#define NA   10000
#define NBLK 5
#define NL   20            // 5 blocks x (2 iW + 2 oW) layers
#define BLOB_W_BYTES 32768               // 128x128 bf16, row=out-feature, XOR-swizzled chunks
#define BLOB_BYTES   33280               // + 128 fp32 folded biases (512 B)

#define LOG2E 1.4426950408889634f
#define LN2   0.6931471805599453f

typedef __bf16 bf16x8 __attribute__((ext_vector_type(8)));
typedef float  f32x4  __attribute__((ext_vector_type(4)));
typedef unsigned short ushort_t;
typedef unsigned int   uint_t;
typedef int4  i4_ma __attribute__((may_alias));
typedef uint2 u2_ma __attribute__((may_alias));

// raw single-instruction transcendentals (v_exp_f32 / v_log_f32); args bounded
#if __has_builtin(__builtin_amdgcn_exp2f)
#define FEXP2(x) __builtin_amdgcn_exp2f(x)
#else
#define FEXP2(x) exp2f(x)
#endif
#if __has_builtin(__builtin_amdgcn_logf)
#define FLOG2(x) __builtin_amdgcn_logf(x)
#else
#define FLOG2(x) log2f(x)
#endif

// ---------------- static device scratch ----------------
__device__ uint8_t g_blob[NL * BLOB_BYTES];   // swizzled bf16 weights + folded f32 biases
__device__ float   g_outs[NBLK * NA * 2];     // per-block per-atom segment sums
__device__ float   g_nh[1];
__device__ float   g_Rf[NA * 3];
__device__ float   g_oWfF[NBLK * 128 * 2];    // ln2-prescaled head weights
__device__ float   g_oBfF[NBLK * 2];          // head biases (unmodified)
__device__ float   g_scF[190];
__device__ float   g_shF[190];

static __device__ __forceinline__ float bf2f(ushort_t u) {
    return __uint_as_float(((uint_t)u) << 16);
}
static __device__ __forceinline__ ushort_t f2bf(float f) {   // RNE (prep only)
    uint_t u = __float_as_uint(f);
    u += 0x7fffu + ((u >> 16) & 1u);
    return (ushort_t)(u >> 16);
}
static __device__ __forceinline__ bf16x8 as_bf16x8(i4_ma v) {
    union { i4_ma i; bf16x8 b; } u; u.i = v; return u.b;
}
// pack 2 floats -> bf16x2 dword by truncation (1 VALU op). Truncation has
// RELATIVE error -- safe because stored u decays with the signal (round-5 lesson).
static __device__ __forceinline__ uint_t pkbf(float a, float b) {
    return __byte_perm(__float_as_uint(a), __float_as_uint(b), 0x7632);
}
// stored activation: u = y/ln2 = log2(1+2^t) - 1 = log2(0.5 + 2^(t-1)).
// The -1 is folded into the layer bias (acc init), so u = log2(0.5 + 2^acc):
// exactly 3 VALU insts (v_exp, v_add, v_log).
static __device__ __forceinline__ float ssp_u(float accv) {
    return FLOG2(0.5f + FEXP2(accv));
}

// dtype auto-detection (validated round 4: inputs are f32; keep as insurance)
static __device__ __forceinline__ bool detect_is_f32(const ushort_t* probe) {
    __shared__ int flag;
    if (threadIdx.x == 0) flag = 0;
    __syncthreads();
    if (threadIdx.x < 256) {
        float v = fabsf(bf2f(probe[2 * threadIdx.x]));
        if (!(v <= 64.0f)) flag = 1;
    }
    __syncthreads();
    return flag != 0;
}
static __device__ __forceinline__ float in_elt(const void* p, int i, bool isf32) {
    return isf32 ? ((const float*)p)[i] : bf2f(((const ushort_t*)p)[i]);
}

// ---------------- zero accumulators ----------------
__global__ void zero_outs()
{
    const int t = blockIdx.x * 256 + threadIdx.x;
    if (t < NBLK * NA * 2) g_outs[t] = 0.0f;
    if (t == 0) g_nh[0] = 0.0f;
}

// ---------------- weight prep ----------------
// blob[L]: row m (out-feature) * 128 bf16; chunk c=k>>3 at 8*((k>>3)^(m&15))+(k&7).
// L==0: W prescaled by log2e (input is raw basis). L>=1: W unscaled (input is u).
// bias = b*log2e - 1 (the -1 implements the s->u shift inside the acc).
__global__ void prep_weights(const void* __restrict__ iW, const void* __restrict__ iB,
                             const void* __restrict__ oW, const void* __restrict__ oB)
{
    const bool isf32 = detect_is_f32((const ushort_t*)iW);
    const int L = blockIdx.x;           // 0..19
    const int b = L >> 2, li = L & 3;
    const void* srcW = (li < 2) ? iW : oW;
    const void* srcB = (li < 2) ? iB : oB;
    const int lyr = (li < 2) ? (b * 2 + li) : (b * 2 + li - 2);
    const int wofs = lyr * 16384;
    const int bofs = lyr * 128;
    uint8_t* blob = g_blob + (size_t)L * BLOB_BYTES;
    ushort_t* dw = (ushort_t*)blob;
    float*    db = (float*)(blob + BLOB_W_BYTES);
    for (int idx = threadIdx.x; idx < 16384; idx += blockDim.x) {
        int k = idx >> 7, n = idx & 127;               // src: W[k][n] (k=in, n=out)
        float w = in_elt(srcW, wofs + k * 128 + n, isf32);
        if (L == 0) w *= LOG2E;
        dw[n * 128 + 8 * ((k >> 3) ^ (n & 15)) + (k & 7)] = f2bf(w);
    }
    for (int m = threadIdx.x; m < 128; m += blockDim.x)
        db[m] = in_elt(srcB, bofs + m, isf32) * LOG2E - 1.0f;
}

// canonical f32 copies; head weights prescaled by ln2 (u -> y factor)
__global__ void prep_misc(const void* __restrict__ R, const void* __restrict__ oWf,
                          const void* __restrict__ oBf, const void* __restrict__ scales,
                          const void* __restrict__ shifts, const void* __restrict__ iW)
{
    const bool isf32 = detect_is_f32((const ushort_t*)iW);
    const int t = blockIdx.x * 256 + threadIdx.x;
    if (t < NA * 3)      g_Rf[t]   = in_elt(R, t, isf32);
    if (t < NBLK * 256)  g_oWfF[t] = LN2 * in_elt(oWf, t, isf32);
    if (t < NBLK * 2)    g_oBfF[t] = in_elt(oBf, t, isf32);
    if (t < 190)         g_scF[t]  = in_elt(scales, t, isf32);
    if (t < 190)         g_shF[t]  = in_elt(shifts, t, isf32);
}

// ---------------- fused per-pair MLP ----------------
// one wave = 32 pairs; 2 x 8KB ping-pong LDS (wave-private, no barriers).
// 16KB LDS/wg -> 10 wg/CU (LDS is the binding occupancy cap).
__global__ __launch_bounds__(64, 3)
void pairs_mlp_kernel(const int* __restrict__ idx_i,
                      const int* __restrict__ idx_j,
                      float* __restrict__ out_rij)       // d_out + 20000 (f32)
{
    __shared__ i4_ma actx[32 * 16];     // 32 rows x 128 bf16, XOR-swizzled 16B chunks
    __shared__ i4_ma acty[32 * 16];

    const int lane = threadIdx.x;
    const int pp = lane & 31;           // pair owned (both half-waves mirror)
    const int p0 = blockIdx.x * 32;
    const int p = p0 + pp;
    const bool valid = (p < NP);

    // ---- phase 0: rij + radial basis -> actx ----
    int ai = 0, aj = 0;
    if (valid) { ai = idx_i[p]; aj = idx_j[p]; }
    float xi0 = g_Rf[3 * ai + 0], xi1 = g_Rf[3 * ai + 1], xi2 = g_Rf[3 * ai + 2];
    float xj0 = g_Rf[3 * aj + 0], xj1 = g_Rf[3 * aj + 1], xj2 = g_Rf[3 * aj + 2];
    float dx = xj0 - xi0, dy = xj1 - xi1, dz = xj2 - xi2;
    float rij = sqrtf(dx * dx + dy * dy + dz * dz + 1e-12f);
    if (lane < 32 && valid) out_rij[p] = rij;

    float fcut = 0.0f;
    if (valid && rij < 10.0f) {
        float xc = rij * 0.1f;
        float x3 = xc * xc * xc;
        fcut = 1.0f + x3 * (-10.0f + xc * (15.0f - 6.0f * xc));
    }
    const float mu0 = 4.5399929762484854e-05f;
    const float dmu = (1.0f - mu0) / 127.0f;
    const float wc = (2.0f / 128.0f) * (1.0f - mu0);
    const float NW2 = -(1.0f / (wc * wc)) * LOG2E;
    float er = FEXP2(-rij * LOG2E);
    const int rs = pp & 15;
    const int c0 = (lane >> 5) * 8;     // each half-wave writes 8 of 16 chunks
#pragma unroll
    for (int ci = 0; ci < 8; ++ci) {
        const int c = c0 + ci;
        uint_t d[4];
#pragma unroll
        for (int jj = 0; jj < 4; ++jj) {
            float m0 = mu0 + (float)(c * 8 + jj * 2 + 0) * dmu;
            float m1 = mu0 + (float)(c * 8 + jj * 2 + 1) * dmu;
            float e0 = er - m0, e1 = er - m1;
            d[jj] = pkbf(fcut * FEXP2(NW2 * e0 * e0), fcut * FEXP2(NW2 * e1 * e1));
        }
        i4_ma pk;
        pk.x = (int)d[0]; pk.y = (int)d[1]; pk.z = (int)d[2]; pk.w = (int)d[3];
        actx[pp * 16 + (c ^ rs)] = pk;
    }

    const int q = lane >> 4;        // quad
    const int l15 = lane & 15;
    const int aseg = valid ? ai : -1;   // sentinel so invalid pairs never merge/fire

    for (int blk = 0; blk < NBLK; ++blk) {
#pragma unroll
        for (int li = 0; li < 4; ++li) {
            const int L = blk * 4 + li;
            const uint8_t* blob = g_blob + (size_t)L * BLOB_BYTES;
            const ushort_t* bw = (const ushort_t*)blob;
            const float* bb = (const float*)(blob + BLOB_W_BYTES);
            // li0: actx->acty, li1: acty->actx (x carries), li2: actx->acty, li3: reads acty
            const i4_ma* src = (li & 1) ? acty : actx;
            i4_ma* dst = (li & 1) ? actx : acty;

            // acc initialized to folded bias (b*log2e - 1): saves the bias add
            f32x4 acc[2][8];
#pragma unroll
            for (int mt = 0; mt < 8; ++mt) {
                const f32x4 bias = *(const f32x4*)(bb + mt * 16 + q * 4);
                acc[0][mt] = bias;
                acc[1][mt] = bias;
            }
#pragma unroll
            for (int kt = 0; kt < 4; ++kt) {
                const int cc = kt * 4 + q;
                bf16x8 bfr0 = as_bf16x8(src[(l15) * 16 + (cc ^ l15)]);
                bf16x8 bfr1 = as_bf16x8(src[(16 + l15) * 16 + (cc ^ l15)]);
#pragma unroll
                for (int mt = 0; mt < 8; ++mt) {
                    bf16x8 afr = as_bf16x8(
                        *(const i4_ma*)(bw + (mt * 16 + l15) * 128 + 8 * (cc ^ l15)));
                    acc[0][mt] = __builtin_amdgcn_mfma_f32_16x16x32_bf16(
                        afr, bfr0, acc[0][mt], 0, 0, 0);
                    acc[1][mt] = __builtin_amdgcn_mfma_f32_16x16x32_bf16(
                        afr, bfr1, acc[1][mt], 0, 0, 0);
                }
            }

            if (li < 3) {
                // acc[nt][mt][rr] = t-1 for feature (mt*16+q*4+rr) of pair (nt*16+l15)
#pragma unroll
                for (int mt = 0; mt < 8; ++mt) {
                    const int c = mt * 2 + (q >> 1);   // feature chunk
#pragma unroll
                    for (int nt = 0; nt < 2; ++nt) {
                        float u0 = ssp_u(acc[nt][mt][0]);
                        float u1 = ssp_u(acc[nt][mt][1]);
                        float u2 = ssp_u(acc[nt][mt][2]);
                        float u3 = ssp_u(acc[nt][mt][3]);
                        u2_ma pk;
                        pk.x = pkbf(u0, u1);
                        pk.y = pkbf(u2, u3);
                        const int rp = nt * 16 + l15;
                        ((u2_ma*)&dst[rp * 16 + (c ^ l15)])[q & 1] = pk;
                    }
                }
            } else {
                // head: out_e = u3 @ (ln2*oWf) + oBf, then sorted-segment reduction
                const float* hw = g_oWfF + blk * 256;
                const float ob0 = g_oBfF[blk * 2 + 0];
                const float ob1 = g_oBfF[blk * 2 + 1];
                float hs[2][2];
#pragma unroll
                for (int nt = 0; nt < 2; ++nt) {
                    float h0 = 0.f, h1 = 0.f;
#pragma unroll
                    for (int mt = 0; mt < 8; ++mt) {
#pragma unroll
                        for (int rr = 0; rr < 4; ++rr) {
                            float u = ssp_u(acc[nt][mt][rr]);
                            const int f = mt * 16 + q * 4 + rr;
                            h0 = fmaf(u, hw[f * 2 + 0], h0);
                            h1 = fmaf(u, hw[f * 2 + 1], h1);
                        }
                    }
                    // butterfly over quads: every lane ends with pair (nt*16+l15)'s total
                    h0 += __shfl_xor(h0, 16, 64);
                    h0 += __shfl_xor(h0, 32, 64);
                    h1 += __shfl_xor(h1, 16, 64);
                    h1 += __shfl_xor(h1, 32, 64);
                    hs[nt][0] = h0; hs[nt][1] = h1;
                }
                // lane pp now selects ITS pair's totals
                float c0v = (pp < 16) ? hs[0][0] : hs[1][0];
                float c1v = (pp < 16) ? hs[0][1] : hs[1][1];
                c0v += ob0; c1v += ob1;
                // segmented inclusive scan over the 32 sorted pairs (runs contiguous)
#pragma unroll
                for (int d = 1; d < 32; d <<= 1) {
                    float t0 = __shfl_up(c0v, d, 64);
                    float t1 = __shfl_up(c1v, d, 64);
                    int   an = __shfl_up(aseg, d, 64);
                    if (pp >= d && an == aseg) { c0v += t0; c1v += t1; }
                }
                int ain = __shfl_down(aseg, 1, 64);
                bool tail = (pp == 31) || (ain != aseg);
                if (lane < 32 && valid && tail) {
                    atomicAdd(&g_outs[(blk * NA + aseg) * 2 + 0], c0v);
                    atomicAdd(&g_outs[(blk * NA + aseg) * 2 + 1], c1v);
                }
            }
        }
    }
}

// ---------------- finalize: scale/shift + nhloss reduction ----------------
__global__ void finalize_kernel(const int* __restrict__ Z,
                                float* __restrict__ out_atoms)   // d_out (f32)
{
    __shared__ float red[256];
    const int a = blockIdx.x * 256 + threadIdx.x;
    float s = 0.f;
    if (a < NA) {
        float v[NBLK][2];
        float t0 = 0.f, t1 = 0.f;
#pragma unroll
        for (int b = 0; b < NBLK; ++b) {
            v[b][0] = g_outs[(b * NA + a) * 2 + 0];
            v[b][1] = g_outs[(b * NA + a) * 2 + 1];
            t0 += v[b][0]; t1 += v[b][1];
        }
        const int z = Z[a];
        out_atoms[a * 2 + 0] = t0 * g_scF[z]      + g_shF[z];
        out_atoms[a * 2 + 1] = t1 * g_scF[95 + z] + g_shF[95 + z];
#pragma unroll
        for (int b = 1; b < NBLK; ++b)
#pragma unroll
            for (int o = 0; o < 2; ++o) {
                float x2 = v[b][o] * v[b][o];
                float p2 = v[b - 1][o] * v[b - 1][o];
                s += x2 / (x2 + p2 + 1e-7f);
            }
    }
    red[threadIdx.x] = s;
    __syncthreads();
    for (int st = 128; st > 0; st >>= 1) {
        if (threadIdx.x < st) red[threadIdx.x] += red[threadIdx.x + st];
        __syncthreads();
    }
    if (threadIdx.x == 0) atomicAdd(&g_nh[0], red[0]);
}

__global__ void nh_write(float* __restrict__ out_nh)
{
    out_nh[0] = g_nh[0] * (1.0f / 20000.0f);
}

// ---------------- launch ----------------
extern "C" void kernel_launch(void* const* d_in, const int* in_sizes, int n_in,
                              void* d_out, int out_size, void* d_ws, size_t ws_size,
                              hipStream_t stream)
{
    const int* Z     = (const int*)d_in[0];
    const void* R    = d_in[1];
    const int* idx_i = (const int*)d_in[2];
    const int* idx_j = (const int*)d_in[3];
    const void* iW   = d_in[4];
    const void* iB   = d_in[5];
    const void* oW   = d_in[6];
    const void* oB   = d_in[7];
    const void* oWf  = d_in[8];
    const void* oBf  = d_in[9];
    const void* scales = d_in[10];
    const void* shifts = d_in[11];

    float* out_f = (float*)d_out;   // [0,20000): outputs  [20000,270000): rij  [270000]: nhloss

    zero_outs<<<(NBLK * NA * 2 + 255) / 256, 256, 0, stream>>>();
    prep_weights<<<NL, 256, 0, stream>>>(iW, iB, oW, oB);
    prep_misc<<<(NA * 3 + 255) / 256, 256, 0, stream>>>(R, oWf, oBf, scales, shifts, iW);
    pairs_mlp_kernel<<<(NP + 31) / 32, 64, 0, stream>>>(idx_i, idx_j, out_f + 2 * NA);
    finalize_kernel<<<(NA + 255) / 256, 256, 0, stream>>>(Z, out_f);
    nh_write<<<1, 1, 0, stream>>>(out_f + 2 * NA + NP);
}